// Round 8
// baseline (155.853 us; speedup 1.0000x reference)
//
#include <hip/hip_runtime.h>

#define A_N   4096
#define EMBED 128
#define MAXO  16
#define DEG   8
#define OBSD  8
#define ORIG  18
#define KCAND 128            // DEG*MAXO candidates per agent
#define G     4              // agents per block
#define NBLK  (A_N / G)      // 1024 blocks
#define NTHR  512            // 8 waves/block -> 4 blocks/CU = 32 waves/CU
#define EL    (MAXO * ORIG)  // 288
#define NQ    (MAXO + 1)     // 17
#define THRES2 (0.02f * 0.02f)

// ---------------------------------------------------------------------------
// Kernel A: 4 source agents, 512 threads.
// 288-wide elems GEMV: 144 e-pairs x splitK2 (288 units, 64 iters, float2
// weights) CONCURRENT with npred-logit GEMV on threads 288..423.
// ---------------------------------------------------------------------------
__global__ __launch_bounds__(NTHR, 8) void enc512_kernel(
    const float* __restrict__ obj_x, const float* __restrict__ obj_pos,
    const float* __restrict__ agent_pos,
    const float* __restrict__ enc_W1, const float* __restrict__ enc_b1,
    const float* __restrict__ enc_W2, const float* __restrict__ enc_b2,
    const float* __restrict__ mdec_Ws, const float* __restrict__ mdec_bs,
    const float* __restrict__ mdec_Wx, const float* __restrict__ mdec_bx,
    const int* __restrict__ obs_edge,
    float* __restrict__ elems_base, int* __restrict__ npred_out)
{
    const int blk = blockIdx.x, tid = threadIdx.x;
    const int i0  = blk * G;
    const int col = tid & 127, q = tid >> 7;

    __shared__ int    on[G][OBSD];
    __shared__ float  msg[G * OBSD][20];
    __shared__ float4 SG[EMBED];          // [c] -> 4 agents
    __shared__ float4 Ep4[4][EMBED];      // split-K4 partials
    __shared__ float4 Eg[EMBED];
    __shared__ float  Lp[2][G * NQ];      // logit split-K2 partials
    __shared__ float  lgts[G][NQ];
    __shared__ float4 Pp[2][EL];          // elems split-K2 partials

    if (tid < G * OBSD) {
        const int g = tid >> 3, d = tid & 7;
        on[g][d] = obs_edge[A_N * OBSD + (i0 + g) * OBSD + d];
    }
    __syncthreads();
    for (int idx = tid; idx < G * OBSD * ORIG; idx += NTHR) {
        const int r = idx / ORIG, c = idx % ORIG;
        const int g = r >> 3, d = r & 7;
        const int o = on[g][d];
        float v;
        if (c < 16) v = obj_x[o * 16 + c];
        else        v = obj_pos[o * 2 + (c - 16)] - agent_pos[(i0 + g) * 2 + (c - 16)];
        msg[r][c] = v;
    }
    __syncthreads();

    // --- h = relu(msg@W1+b1), segment-sum; thread (col,q) -> agent q ---
    {
        float w1[ORIG];
#pragma unroll
        for (int c = 0; c < ORIG; ++c) w1[c] = enc_W1[c * EMBED + col];
        const float b1 = enc_b1[col];
        float acc = 0.f;
#pragma unroll
        for (int d = 0; d < OBSD; ++d) {
            const int r = q * OBSD + d;
            const float4* mr = (const float4*)&msg[r][0];
            const float4 m0 = mr[0], m1 = mr[1], m2 = mr[2], m3 = mr[3];
            const float2 m4 = *(const float2*)&msg[r][16];
            float h = b1
                + m0.x*w1[0]  + m0.y*w1[1]  + m0.z*w1[2]  + m0.w*w1[3]
                + m1.x*w1[4]  + m1.y*w1[5]  + m1.z*w1[6]  + m1.w*w1[7]
                + m2.x*w1[8]  + m2.y*w1[9]  + m2.z*w1[10] + m2.w*w1[11]
                + m3.x*w1[12] + m3.y*w1[13] + m3.z*w1[14] + m3.w*w1[15]
                + m4.x*w1[16] + m4.y*w1[17];
            acc += fmaxf(h, 0.f);
        }
        ((float*)&SG[col])[q] = acc;
    }
    __syncthreads();

    // --- enc = S@W2 + b2, split-K4 ---
    {
        float4 acc = {0.f, 0.f, 0.f, 0.f};
        const int c0 = 32 * q;
#pragma unroll 8
        for (int c = c0; c < c0 + 32; ++c) {
            const float4 s = SG[c];
            const float  w = enc_W2[c * EMBED + col];
            acc.x += s.x * w; acc.y += s.y * w; acc.z += s.z * w; acc.w += s.w * w;
        }
        Ep4[q][col] = acc;
    }
    __syncthreads();
    if (tid < EMBED) {
        const float4 a = Ep4[0][tid], b = Ep4[1][tid], c = Ep4[2][tid], d = Ep4[3][tid];
        const float bb = enc_b2[tid];
        float4 e;
        e.x = a.x + b.x + c.x + d.x + bb;
        e.y = a.y + b.y + c.y + d.y + bb;
        e.z = a.z + b.z + c.z + d.z + bb;
        e.w = a.w + b.w + c.w + d.w + bb;
        Eg[tid] = e;
    }
    __syncthreads();

    // --- elems partials (288 units, e-pairs, float2 W) || npred-logit partials ---
    if (tid < 288) {
        const int pp = tid / 144, pe = tid % 144;
        const int e0 = 2 * pe;
        float4 a0 = {0.f,0.f,0.f,0.f}, a1 = {0.f,0.f,0.f,0.f};
        const int c0 = 64 * pp;
#pragma unroll 8
        for (int c = c0; c < c0 + 64; ++c) {
            const float4 s = Eg[c];
            const float2 w2 = *(const float2*)&mdec_Wx[c * EL + e0];
            a0.x += s.x*w2.x; a0.y += s.y*w2.x; a0.z += s.z*w2.x; a0.w += s.w*w2.x;
            a1.x += s.x*w2.y; a1.y += s.y*w2.y; a1.z += s.z*w2.y; a1.w += s.w*w2.y;
        }
        Pp[pp][e0] = a0; Pp[pp][e0 + 1] = a1;
    } else if (tid < 424) {
        const int lu = tid - 288, pp = lu / 68, lq = lu % 68;
        const int g = lq / NQ, qq = lq % NQ;
        float v = 0.f;
        const int c0 = 64 * pp;
#pragma unroll 8
        for (int c = c0; c < c0 + 64; ++c)
            v += ((const float*)&Eg[c])[g] * mdec_Ws[c * NQ + qq];
        Lp[pp][lq] = v;
    }
    __syncthreads();

    if (tid < EL) {
        const float4 a = Pp[0][tid], b = Pp[1][tid];
        const float bx = mdec_bx[tid];
        elems_base[(size_t)(i0 + 0) * EL + tid] = a.x + b.x + bx;
        elems_base[(size_t)(i0 + 1) * EL + tid] = a.y + b.y + bx;
        elems_base[(size_t)(i0 + 2) * EL + tid] = a.z + b.z + bx;
        elems_base[(size_t)(i0 + 3) * EL + tid] = a.w + b.w + bx;
    } else if (tid < EL + G * NQ) {
        const int lq = tid - EL;
        const int g = lq / NQ, qq = lq % NQ;
        lgts[g][qq] = Lp[0][lq] + Lp[1][lq] + mdec_bs[qq];
    }
    __syncthreads();
    if (tid < G) {
        int best = 0; float bv = lgts[tid][0];
        for (int qq = 1; qq < NQ; ++qq) if (lgts[tid][qq] > bv) { bv = lgts[tid][qq]; best = qq; }
        npred_out[i0 + tid] = best;
    }
}

// ---------------------------------------------------------------------------
// Kernel B: 4 target agents, 512 threads = 8 waves; wave-pair per agent for
// compaction/dedup; decode GEMV as e-pairs||logits like kernel A.
// ---------------------------------------------------------------------------
__global__ __launch_bounds__(NTHR, 8) void merge512_kernel(
    const float* __restrict__ agent_pos,
    const float* __restrict__ menc_W1, const float* __restrict__ menc_b1,
    const float* __restrict__ menc_W2, const float* __restrict__ menc_b2,
    const float* __restrict__ dec_Ws, const float* __restrict__ dec_bs,
    const float* __restrict__ dec_Wx, const float* __restrict__ dec_bx,
    const int* __restrict__ comm_edge,
    const float* __restrict__ elems_base, const int* __restrict__ npred,
    float* __restrict__ out_dec, float* __restrict__ out_batch,
    float* __restrict__ out_mask)
{
    const int blk = blockIdx.x, tid = threadIdx.x;
    const int i0  = blk * G;
    const int col = tid & 127, q = tid >> 7;
    const int lane = tid & 63, wv = tid >> 6;
    const int w = wv >> 1, half = wv & 1;

    __shared__ int    jn[G][DEG];
    __shared__ float  relx[G][DEG], rely[G][DEG];
    __shared__ int    npd[G][DEG];
    __shared__ float2 pxy[G][KCAND];
    __shared__ int    vl[G][KCAND];      // compacted valid indices (ascending)
    __shared__ float2 pv[G][KCAND];      // compacted valid positions
    __shared__ int    wcv[G][2], kcv[G][2];
    __shared__ int    nv[G], kcnt[G];
    __shared__ int    klist[G][MAXO];
    __shared__ float  kc[G][MAXO][20];
    __shared__ float4 Hs[EMBED];
    __shared__ float4 Mp4[4][EMBED];
    __shared__ float4 Mg[EMBED];
    __shared__ float  Lp[2][G * NQ];
    __shared__ float  lg2[G][NQ];
    __shared__ int    n2s[G];
    __shared__ float4 Pp[2][EL];

    if (tid < G * DEG) {
        const int g = tid >> 3, d = tid & 7;
        const int e = (i0 + g) * DEG + d;
        const int j  = comm_edge[e];
        const int ii = comm_edge[A_N * DEG + e];
        jn[g][d]  = j;
        relx[g][d] = agent_pos[j * 2 + 0] - agent_pos[ii * 2 + 0];
        rely[g][d] = agent_pos[j * 2 + 1] - agent_pos[ii * 2 + 1];
        npd[g][d] = npred[j];
    }
    __syncthreads();

    // --- positions + valid, compacted valid list+positions ---
    const int k = 64 * half + lane;
    const int kd = k >> 4, km = k & 15;
    float2 p;
    int val;
    {
        const float* eb = elems_base + (size_t)jn[w][kd] * EL + km * ORIG;
        p = *(const float2*)(eb + 16);
        p.x += relx[w][kd]; p.y += rely[w][kd];
        pxy[w][k] = p;
        val = (km < npd[w][kd]) ? 1 : 0;
        const unsigned long long bal = __ballot(val);
        const int pref = (int)__popcll(bal << (63 - lane));
        if (lane == 63) wcv[w][half] = (int)__popcll(bal);
        __syncthreads();
        const int base = half ? wcv[w][0] : 0;
        if (val) { vl[w][base + pref - 1] = k; pv[w][base + pref - 1] = p; }
        if (lane == 0 && half == 0) nv[w] = wcv[w][0] + wcv[w][1];
        __syncthreads();
    }

    // --- dedup + cap 15: scan compacted streams (pipelined, no sqrt) ---
    {
        const int nvg = nv[w];
        int dup = 0;
        for (int idx = 0; idx < nvg; ++idx) {
            const int k1 = vl[w][idx];
            if (k1 >= k) break;                       // ascending list
            const float2 p1 = pv[w][idx];
            const float dx = p1.x - p.x, dy = p1.y - p.y;
            if (dx * dx + dy * dy < THRES2) dup = 1;
        }
        const int kp = (val && !dup) ? 1 : 0;
        const unsigned long long bal = __ballot(kp);
        const int pref = (int)__popcll(bal << (63 - lane));
        if (lane == 63) kcv[w][half] = (int)__popcll(bal);
        __syncthreads();
        const int cnt = (half ? kcv[w][0] : 0) + pref;
        if (kp && cnt <= MAXO - 1) klist[w][cnt - 1] = k;
        if (lane == 0 && half == 0) {
            const int tot = kcv[w][0] + kcv[w][1];
            kcnt[w] = (tot < MAXO - 1) ? tot : (MAXO - 1);
        }
        __syncthreads();
    }

    // --- gather kept rows ---
    for (int idx = tid; idx < G * EL; idx += NTHR) {
        const int g = idx / EL, rem = idx % EL;
        const int s = rem / ORIG, c = rem % ORIG;
        if (s < kcnt[g]) {
            const int kk = klist[g][s], d = kk >> 4, m = kk & 15;
            float v;
            if (c < 16) v = elems_base[(size_t)jn[g][d] * EL + m * ORIG + c];
            else        v = (c == 16) ? pxy[g][kk].x : pxy[g][kk].y;
            kc[g][s][c] = v;
        }
    }
    __syncthreads();

    // --- hsum: thread (col,q) -> agent q over <=15 kept rows ---
    {
        float w1[ORIG];
#pragma unroll
        for (int c = 0; c < ORIG; ++c) w1[c] = menc_W1[c * EMBED + col];
        const float b1 = menc_b1[col];
        const int nk = kcnt[q];
        float hs = 0.f;
        for (int s = 0; s < nk; ++s) {
            const float4* mr = (const float4*)&kc[q][s][0];
            const float4 m0 = mr[0], m1 = mr[1], m2 = mr[2], m3 = mr[3];
            const float2 m4 = *(const float2*)&kc[q][s][16];
            float h = b1
                + m0.x*w1[0]  + m0.y*w1[1]  + m0.z*w1[2]  + m0.w*w1[3]
                + m1.x*w1[4]  + m1.y*w1[5]  + m1.z*w1[6]  + m1.w*w1[7]
                + m2.x*w1[8]  + m2.y*w1[9]  + m2.z*w1[10] + m2.w*w1[11]
                + m3.x*w1[12] + m3.y*w1[13] + m3.z*w1[14] + m3.w*w1[15]
                + m4.x*w1[16] + m4.y*w1[17];
            hs += fmaxf(h, 0.f);
        }
        ((float*)&Hs[col])[q] = hs;
    }
    __syncthreads();

    // --- merged = hsum@W2 + b2, split-K4 ---
    {
        float4 acc = {0.f, 0.f, 0.f, 0.f};
        const int c0 = 32 * q;
#pragma unroll 8
        for (int c = c0; c < c0 + 32; ++c) {
            const float4 s = Hs[c];
            const float  ww = menc_W2[c * EMBED + col];
            acc.x += s.x * ww; acc.y += s.y * ww; acc.z += s.z * ww; acc.w += s.w * ww;
        }
        Mp4[q][col] = acc;
    }
    __syncthreads();
    if (tid < EMBED) {
        const float4 a = Mp4[0][tid], b = Mp4[1][tid], c = Mp4[2][tid], d = Mp4[3][tid];
        const float bb = menc_b2[tid];
        float4 e;
        e.x = a.x + b.x + c.x + d.x + bb;
        e.y = a.y + b.y + c.y + d.y + bb;
        e.z = a.z + b.z + c.z + d.z + bb;
        e.w = a.w + b.w + c.w + d.w + bb;
        Mg[tid] = e;
    }
    __syncthreads();

    // --- decode partials (e-pairs, float2 W) || n2-logit partials ---
    if (tid < 288) {
        const int pp = tid / 144, pe = tid % 144;
        const int e0 = 2 * pe;
        float4 a0 = {0.f,0.f,0.f,0.f}, a1 = {0.f,0.f,0.f,0.f};
        const int c0 = 64 * pp;
#pragma unroll 8
        for (int c = c0; c < c0 + 64; ++c) {
            const float4 s = Mg[c];
            const float2 w2 = *(const float2*)&dec_Wx[c * EL + e0];
            a0.x += s.x*w2.x; a0.y += s.y*w2.x; a0.z += s.z*w2.x; a0.w += s.w*w2.x;
            a1.x += s.x*w2.y; a1.y += s.y*w2.y; a1.z += s.z*w2.y; a1.w += s.w*w2.y;
        }
        Pp[pp][e0] = a0; Pp[pp][e0 + 1] = a1;
    } else if (tid < 424) {
        const int lu = tid - 288, pp = lu / 68, lq = lu % 68;
        const int g = lq / NQ, qq = lq % NQ;
        float v = 0.f;
        const int c0 = 64 * pp;
#pragma unroll 8
        for (int c = c0; c < c0 + 64; ++c)
            v += ((const float*)&Mg[c])[g] * dec_Ws[c * NQ + qq];
        Lp[pp][lq] = v;
    }
    __syncthreads();

    // decode combine into registers (no n2 dependency) || logit combine
    float4 dreg = {0.f, 0.f, 0.f, 0.f};
    if (tid < EL) {
        const float4 a = Pp[0][tid], b = Pp[1][tid];
        const float bx = dec_bx[tid];
        dreg.x = a.x + b.x + bx; dreg.y = a.y + b.y + bx;
        dreg.z = a.z + b.z + bx; dreg.w = a.w + b.w + bx;
    } else if (tid < EL + G * NQ) {
        const int lq = tid - EL;
        const int g = lq / NQ, qq = lq % NQ;
        lg2[g][qq] = Lp[0][lq] + Lp[1][lq] + dec_bs[qq];
    }
    __syncthreads();
    if (tid < G) {
        int best = 0; float bv = lg2[tid][0];
        for (int qq = 1; qq < NQ; ++qq) if (lg2[tid][qq] > bv) { bv = lg2[tid][qq]; best = qq; }
        n2s[tid] = best;
    }
    __syncthreads();

    if (tid < EL) {
        const int m = tid / ORIG;
        out_dec[(size_t)(i0 + 0) * EL + tid] = (m < n2s[0]) ? dreg.x : 0.f;
        out_dec[(size_t)(i0 + 1) * EL + tid] = (m < n2s[1]) ? dreg.y : 0.f;
        out_dec[(size_t)(i0 + 2) * EL + tid] = (m < n2s[2]) ? dreg.z : 0.f;
        out_dec[(size_t)(i0 + 3) * EL + tid] = (m < n2s[3]) ? dreg.w : 0.f;
    } else if (tid >= NTHR - G * MAXO) {
        const int idx = tid - (NTHR - G * MAXO);
        const int g = idx >> 4, m = idx & 15;
        out_batch[(i0 + g) * MAXO + m] = (float)(i0 + g);
        out_mask[(i0 + g) * MAXO + m]  = (m < n2s[g]) ? 1.f : 0.f;
    }
}

extern "C" void kernel_launch(void* const* d_in, const int* in_sizes, int n_in,
                              void* d_out, int out_size, void* d_ws, size_t ws_size,
                              hipStream_t stream)
{
    const float* obj_x     = (const float*)d_in[0];
    const float* obj_pos   = (const float*)d_in[1];
    const float* agent_pos = (const float*)d_in[2];
    const float* enc_W1    = (const float*)d_in[3];
    const float* enc_b1    = (const float*)d_in[4];
    const float* enc_W2    = (const float*)d_in[5];
    const float* enc_b2    = (const float*)d_in[6];
    const float* mdec_Ws   = (const float*)d_in[7];
    const float* mdec_bs   = (const float*)d_in[8];
    const float* mdec_Wx   = (const float*)d_in[9];
    const float* mdec_bx   = (const float*)d_in[10];
    const float* menc_W1   = (const float*)d_in[11];
    const float* menc_b1   = (const float*)d_in[12];
    const float* menc_W2   = (const float*)d_in[13];
    const float* menc_b2   = (const float*)d_in[14];
    const float* dec_Ws    = (const float*)d_in[15];
    const float* dec_bs    = (const float*)d_in[16];
    const float* dec_Wx    = (const float*)d_in[17];
    const float* dec_bx    = (const float*)d_in[18];
    const int*   obs_edge  = (const int*)d_in[19];
    const int*   comm_edge = (const int*)d_in[20];

    float* elems_base = (float*)d_ws;                                   // 4096*288 f32
    int*   npred      = (int*)((char*)d_ws + (size_t)A_N * EL * sizeof(float));

    float* out_dec   = (float*)d_out;
    float* out_batch = out_dec + (size_t)A_N * EL;
    float* out_mask  = out_batch + (size_t)A_N * MAXO;

    enc512_kernel<<<NBLK, NTHR, 0, stream>>>(
        obj_x, obj_pos, agent_pos, enc_W1, enc_b1, enc_W2, enc_b2,
        mdec_Ws, mdec_bs, mdec_Wx, mdec_bx, obs_edge, elems_base, npred);

    merge512_kernel<<<NBLK, NTHR, 0, stream>>>(
        agent_pos, menc_W1, menc_b1, menc_W2, menc_b2,
        dec_Ws, dec_bs, dec_Wx, dec_bx, comm_edge,
        elems_base, npred, out_dec, out_batch, out_mask);
}

// Round 9
// 153.758 us; speedup vs baseline: 1.0136x; 1.0136x over previous
//
#include <hip/hip_runtime.h>

#define A_N   4096
#define EMBED 128
#define MAXO  16
#define DEG   8
#define OBSD  8
#define ORIG  18
#define KCAND 128            // DEG*MAXO candidates per agent
#define G     4              // agents per block
#define NBLK  (A_N / G)      // 1024 blocks
#define NTHR  512            // 8 waves/block -> 4 blocks/CU = 32 waves/CU
#define EL    (MAXO * ORIG)  // 288
#define NQ    (MAXO + 1)     // 17
#define THRES2 (0.02f * 0.02f)

// concurrent-phase thread ranges (WAVE-ALIGNED: no wave runs two loops)
#define EP_END    288        // e-pair units: threads 0..287 (waves 0..4L)
#define LG_BEG    320        // logit units:  threads 320..455 (waves 5..7L)
#define LG_END    456

// ---------------------------------------------------------------------------
// Kernel A: 4 source agents, 512 threads.
// ---------------------------------------------------------------------------
__global__ __launch_bounds__(NTHR, 8) void enc512_kernel(
    const float* __restrict__ obj_x, const float* __restrict__ obj_pos,
    const float* __restrict__ agent_pos,
    const float* __restrict__ enc_W1, const float* __restrict__ enc_b1,
    const float* __restrict__ enc_W2, const float* __restrict__ enc_b2,
    const float* __restrict__ mdec_Ws, const float* __restrict__ mdec_bs,
    const float* __restrict__ mdec_Wx, const float* __restrict__ mdec_bx,
    const int* __restrict__ obs_edge,
    float* __restrict__ elems_base, int* __restrict__ npred_out,
    float2* __restrict__ pxy_base)
{
    const int blk = blockIdx.x, tid = threadIdx.x;
    const int i0  = blk * G;
    const int col = tid & 127, q = tid >> 7;

    __shared__ int    on[G][OBSD];
    __shared__ float  msg[G * OBSD][20];
    __shared__ float4 SG[EMBED];          // [c] -> 4 agents
    __shared__ float4 Ep4[4][EMBED];      // split-K4 partials
    __shared__ float4 Eg[EMBED];
    __shared__ float  Lp[2][G * NQ];      // logit split-K2 partials
    __shared__ float  lgts[G][NQ];
    __shared__ float4 Pp[2][EL];          // elems split-K2 partials

    if (tid < G * OBSD) {
        const int g = tid >> 3, d = tid & 7;
        on[g][d] = obs_edge[A_N * OBSD + (i0 + g) * OBSD + d];
    }
    __syncthreads();
    for (int idx = tid; idx < G * OBSD * ORIG; idx += NTHR) {
        const int r = idx / ORIG, c = idx % ORIG;
        const int g = r >> 3, d = r & 7;
        const int o = on[g][d];
        float v;
        if (c < 16) v = obj_x[o * 16 + c];
        else        v = obj_pos[o * 2 + (c - 16)] - agent_pos[(i0 + g) * 2 + (c - 16)];
        msg[r][c] = v;
    }
    __syncthreads();

    // --- h = relu(msg@W1+b1), segment-sum; thread (col,q) -> agent q ---
    {
        float w1[ORIG];
#pragma unroll
        for (int c = 0; c < ORIG; ++c) w1[c] = enc_W1[c * EMBED + col];
        const float b1 = enc_b1[col];
        float acc = 0.f;
#pragma unroll
        for (int d = 0; d < OBSD; ++d) {
            const int r = q * OBSD + d;
            const float4* mr = (const float4*)&msg[r][0];
            const float4 m0 = mr[0], m1 = mr[1], m2 = mr[2], m3 = mr[3];
            const float2 m4 = *(const float2*)&msg[r][16];
            float h = b1
                + m0.x*w1[0]  + m0.y*w1[1]  + m0.z*w1[2]  + m0.w*w1[3]
                + m1.x*w1[4]  + m1.y*w1[5]  + m1.z*w1[6]  + m1.w*w1[7]
                + m2.x*w1[8]  + m2.y*w1[9]  + m2.z*w1[10] + m2.w*w1[11]
                + m3.x*w1[12] + m3.y*w1[13] + m3.z*w1[14] + m3.w*w1[15]
                + m4.x*w1[16] + m4.y*w1[17];
            acc += fmaxf(h, 0.f);
        }
        ((float*)&SG[col])[q] = acc;
    }
    __syncthreads();

    // --- enc = S@W2 + b2, split-K4 ---
    {
        float4 acc = {0.f, 0.f, 0.f, 0.f};
        const int c0 = 32 * q;
#pragma unroll 8
        for (int c = c0; c < c0 + 32; ++c) {
            const float4 s = SG[c];
            const float  w = enc_W2[c * EMBED + col];
            acc.x += s.x * w; acc.y += s.y * w; acc.z += s.z * w; acc.w += s.w * w;
        }
        Ep4[q][col] = acc;
    }
    __syncthreads();
    if (tid < EMBED) {
        const float4 a = Ep4[0][tid], b = Ep4[1][tid], c = Ep4[2][tid], d = Ep4[3][tid];
        const float bb = enc_b2[tid];
        float4 e;
        e.x = a.x + b.x + c.x + d.x + bb;
        e.y = a.y + b.y + c.y + d.y + bb;
        e.z = a.z + b.z + c.z + d.z + bb;
        e.w = a.w + b.w + c.w + d.w + bb;
        Eg[tid] = e;
    }
    __syncthreads();

    // --- elems partials (waves 0-4) || npred-logit partials (waves 5-7) ---
    if (tid < EP_END) {
        const int pp = tid / 144, pe = tid % 144;
        const int e0 = 2 * pe;
        float4 a0 = {0.f,0.f,0.f,0.f}, a1 = {0.f,0.f,0.f,0.f};
        const int c0 = 64 * pp;
#pragma unroll 8
        for (int c = c0; c < c0 + 64; ++c) {
            const float4 s = Eg[c];
            const float2 w2 = *(const float2*)&mdec_Wx[c * EL + e0];
            a0.x += s.x*w2.x; a0.y += s.y*w2.x; a0.z += s.z*w2.x; a0.w += s.w*w2.x;
            a1.x += s.x*w2.y; a1.y += s.y*w2.y; a1.z += s.z*w2.y; a1.w += s.w*w2.y;
        }
        Pp[pp][e0] = a0; Pp[pp][e0 + 1] = a1;
    } else if (tid >= LG_BEG && tid < LG_END) {
        const int lu = tid - LG_BEG, pp = lu / 68, lq = lu % 68;
        const int g = lq / NQ, qq = lq % NQ;
        float v = 0.f;
        const int c0 = 64 * pp;
#pragma unroll 8
        for (int c = c0; c < c0 + 64; ++c)
            v += ((const float*)&Eg[c])[g] * mdec_Ws[c * NQ + qq];
        Lp[pp][lq] = v;
    }
    __syncthreads();

    if (tid < EL) {
        const float4 a = Pp[0][tid], b = Pp[1][tid];
        const float bx = mdec_bx[tid];
        elems_base[(size_t)(i0 + 0) * EL + tid] = a.x + b.x + bx;
        elems_base[(size_t)(i0 + 1) * EL + tid] = a.y + b.y + bx;
        elems_base[(size_t)(i0 + 2) * EL + tid] = a.z + b.z + bx;
        elems_base[(size_t)(i0 + 3) * EL + tid] = a.w + b.w + bx;
    } else if (tid < EL + G * NQ) {
        const int lq = tid - EL;
        const int g = lq / NQ, qq = lq % NQ;
        lgts[g][qq] = Lp[0][lq] + Lp[1][lq] + mdec_bs[qq];
    } else if (tid < EL + G * NQ + G * MAXO) {
        // coalesced positions side-array: pxy_base[(i0+g)*16+m] = elems cols 16,17
        const int u = tid - (EL + G * NQ);
        const int g = u >> 4, m = u & 15;
        const int e16 = m * ORIG + 16, e17 = e16 + 1;
        const float px = ((const float*)&Pp[0][e16])[g] + ((const float*)&Pp[1][e16])[g]
                       + mdec_bx[e16];
        const float py = ((const float*)&Pp[0][e17])[g] + ((const float*)&Pp[1][e17])[g]
                       + mdec_bx[e17];
        pxy_base[(size_t)(i0 + g) * MAXO + m] = make_float2(px, py);
    }
    __syncthreads();
    if (tid < G) {
        int best = 0; float bv = lgts[tid][0];
        for (int qq = 1; qq < NQ; ++qq) if (lgts[tid][qq] > bv) { bv = lgts[tid][qq]; best = qq; }
        npred_out[i0 + tid] = best;
    }
}

// ---------------------------------------------------------------------------
// Kernel B: 4 target agents, 512 threads = 8 waves; wave-pair per agent for
// compaction/dedup; decode GEMV wave-aligned-concurrent with n2 logits.
// ---------------------------------------------------------------------------
__global__ __launch_bounds__(NTHR, 8) void merge512_kernel(
    const float* __restrict__ agent_pos,
    const float* __restrict__ menc_W1, const float* __restrict__ menc_b1,
    const float* __restrict__ menc_W2, const float* __restrict__ menc_b2,
    const float* __restrict__ dec_Ws, const float* __restrict__ dec_bs,
    const float* __restrict__ dec_Wx, const float* __restrict__ dec_bx,
    const int* __restrict__ comm_edge,
    const float* __restrict__ elems_base, const int* __restrict__ npred,
    const float2* __restrict__ pxy_base,
    float* __restrict__ out_dec, float* __restrict__ out_batch,
    float* __restrict__ out_mask)
{
    const int blk = blockIdx.x, tid = threadIdx.x;
    const int i0  = blk * G;
    const int col = tid & 127, q = tid >> 7;
    const int lane = tid & 63, wv = tid >> 6;
    const int w = wv >> 1, half = wv & 1;

    __shared__ int    jn[G][DEG];
    __shared__ float  relx[G][DEG], rely[G][DEG];
    __shared__ int    npd[G][DEG];
    __shared__ float2 pxy[G][KCAND];
    __shared__ int    vl[G][KCAND];      // compacted valid indices (ascending)
    __shared__ float2 pv[G][KCAND];      // compacted valid positions
    __shared__ int    wcv[G][2], kcv[G][2];
    __shared__ int    nv[G], kcnt[G];
    __shared__ int    klist[G][MAXO];
    __shared__ float  kc[G][MAXO][20];
    __shared__ float4 Hs[EMBED];
    __shared__ float4 Mp4[4][EMBED];
    __shared__ float4 Mg[EMBED];
    __shared__ float  Lp[2][G * NQ];
    __shared__ float  lg2[G][NQ];
    __shared__ int    n2s[G];
    __shared__ float4 Pp[2][EL];

    if (tid < G * DEG) {
        const int g = tid >> 3, d = tid & 7;
        const int e = (i0 + g) * DEG + d;
        const int j  = comm_edge[e];
        const int ii = comm_edge[A_N * DEG + e];
        jn[g][d]  = j;
        relx[g][d] = agent_pos[j * 2 + 0] - agent_pos[ii * 2 + 0];
        rely[g][d] = agent_pos[j * 2 + 1] - agent_pos[ii * 2 + 1];
        npd[g][d] = npred[j];
    }
    __syncthreads();

    // --- positions (coalesced via pxy_base) + valid, compacted list ---
    const int k = 64 * half + lane;
    const int kd = k >> 4, km = k & 15;
    float2 p;
    int val;
    {
        p = pxy_base[(size_t)jn[w][kd] * MAXO + km];
        p.x += relx[w][kd]; p.y += rely[w][kd];
        pxy[w][k] = p;
        val = (km < npd[w][kd]) ? 1 : 0;
        const unsigned long long bal = __ballot(val);
        const int pref = (int)__popcll(bal << (63 - lane));
        if (lane == 63) wcv[w][half] = (int)__popcll(bal);
        __syncthreads();
        const int base = half ? wcv[w][0] : 0;
        if (val) { vl[w][base + pref - 1] = k; pv[w][base + pref - 1] = p; }
        if (lane == 0 && half == 0) nv[w] = wcv[w][0] + wcv[w][1];
        __syncthreads();
    }

    // --- dedup + cap 15: scan compacted streams (pipelined, no sqrt) ---
    {
        const int nvg = nv[w];
        int dup = 0;
        for (int idx = 0; idx < nvg; ++idx) {
            const int k1 = vl[w][idx];
            if (k1 >= k) break;                       // ascending list
            const float2 p1 = pv[w][idx];
            const float dx = p1.x - p.x, dy = p1.y - p.y;
            if (dx * dx + dy * dy < THRES2) dup = 1;
        }
        const int kp = (val && !dup) ? 1 : 0;
        const unsigned long long bal = __ballot(kp);
        const int pref = (int)__popcll(bal << (63 - lane));
        if (lane == 63) kcv[w][half] = (int)__popcll(bal);
        __syncthreads();
        const int cnt = (half ? kcv[w][0] : 0) + pref;
        if (kp && cnt <= MAXO - 1) klist[w][cnt - 1] = k;
        if (lane == 0 && half == 0) {
            const int tot = kcv[w][0] + kcv[w][1];
            kcnt[w] = (tot < MAXO - 1) ? tot : (MAXO - 1);
        }
        __syncthreads();
    }

    // --- gather kept rows ---
    for (int idx = tid; idx < G * EL; idx += NTHR) {
        const int g = idx / EL, rem = idx % EL;
        const int s = rem / ORIG, c = rem % ORIG;
        if (s < kcnt[g]) {
            const int kk = klist[g][s], d = kk >> 4, m = kk & 15;
            float v;
            if (c < 16) v = elems_base[(size_t)jn[g][d] * EL + m * ORIG + c];
            else        v = (c == 16) ? pxy[g][kk].x : pxy[g][kk].y;
            kc[g][s][c] = v;
        }
    }
    __syncthreads();

    // --- hsum: thread (col,q) -> agent q over <=15 kept rows ---
    {
        float w1[ORIG];
#pragma unroll
        for (int c = 0; c < ORIG; ++c) w1[c] = menc_W1[c * EMBED + col];
        const float b1 = menc_b1[col];
        const int nk = kcnt[q];
        float hs = 0.f;
        for (int s = 0; s < nk; ++s) {
            const float4* mr = (const float4*)&kc[q][s][0];
            const float4 m0 = mr[0], m1 = mr[1], m2 = mr[2], m3 = mr[3];
            const float2 m4 = *(const float2*)&kc[q][s][16];
            float h = b1
                + m0.x*w1[0]  + m0.y*w1[1]  + m0.z*w1[2]  + m0.w*w1[3]
                + m1.x*w1[4]  + m1.y*w1[5]  + m1.z*w1[6]  + m1.w*w1[7]
                + m2.x*w1[8]  + m2.y*w1[9]  + m2.z*w1[10] + m2.w*w1[11]
                + m3.x*w1[12] + m3.y*w1[13] + m3.z*w1[14] + m3.w*w1[15]
                + m4.x*w1[16] + m4.y*w1[17];
            hs += fmaxf(h, 0.f);
        }
        ((float*)&Hs[col])[q] = hs;
    }
    __syncthreads();

    // --- merged = hsum@W2 + b2, split-K4 ---
    {
        float4 acc = {0.f, 0.f, 0.f, 0.f};
        const int c0 = 32 * q;
#pragma unroll 8
        for (int c = c0; c < c0 + 32; ++c) {
            const float4 s = Hs[c];
            const float  ww = menc_W2[c * EMBED + col];
            acc.x += s.x * ww; acc.y += s.y * ww; acc.z += s.z * ww; acc.w += s.w * ww;
        }
        Mp4[q][col] = acc;
    }
    __syncthreads();
    if (tid < EMBED) {
        const float4 a = Mp4[0][tid], b = Mp4[1][tid], c = Mp4[2][tid], d = Mp4[3][tid];
        const float bb = menc_b2[tid];
        float4 e;
        e.x = a.x + b.x + c.x + d.x + bb;
        e.y = a.y + b.y + c.y + d.y + bb;
        e.z = a.z + b.z + c.z + d.z + bb;
        e.w = a.w + b.w + c.w + d.w + bb;
        Mg[tid] = e;
    }
    __syncthreads();

    // --- decode partials (waves 0-4) || n2-logit partials (waves 5-7) ---
    if (tid < EP_END) {
        const int pp = tid / 144, pe = tid % 144;
        const int e0 = 2 * pe;
        float4 a0 = {0.f,0.f,0.f,0.f}, a1 = {0.f,0.f,0.f,0.f};
        const int c0 = 64 * pp;
#pragma unroll 8
        for (int c = c0; c < c0 + 64; ++c) {
            const float4 s = Mg[c];
            const float2 w2 = *(const float2*)&dec_Wx[c * EL + e0];
            a0.x += s.x*w2.x; a0.y += s.y*w2.x; a0.z += s.z*w2.x; a0.w += s.w*w2.x;
            a1.x += s.x*w2.y; a1.y += s.y*w2.y; a1.z += s.z*w2.y; a1.w += s.w*w2.y;
        }
        Pp[pp][e0] = a0; Pp[pp][e0 + 1] = a1;
    } else if (tid >= LG_BEG && tid < LG_END) {
        const int lu = tid - LG_BEG, pp = lu / 68, lq = lu % 68;
        const int g = lq / NQ, qq = lq % NQ;
        float v = 0.f;
        const int c0 = 64 * pp;
#pragma unroll 8
        for (int c = c0; c < c0 + 64; ++c)
            v += ((const float*)&Mg[c])[g] * dec_Ws[c * NQ + qq];
        Lp[pp][lq] = v;
    }
    __syncthreads();

    // decode combine into registers (no n2 dependency) || logit combine
    float4 dreg = {0.f, 0.f, 0.f, 0.f};
    if (tid < EL) {
        const float4 a = Pp[0][tid], b = Pp[1][tid];
        const float bx = dec_bx[tid];
        dreg.x = a.x + b.x + bx; dreg.y = a.y + b.y + bx;
        dreg.z = a.z + b.z + bx; dreg.w = a.w + b.w + bx;
    } else if (tid < EL + G * NQ) {
        const int lq = tid - EL;
        const int g = lq / NQ, qq = lq % NQ;
        lg2[g][qq] = Lp[0][lq] + Lp[1][lq] + dec_bs[qq];
    }
    __syncthreads();
    if (tid < G) {
        int best = 0; float bv = lg2[tid][0];
        for (int qq = 1; qq < NQ; ++qq) if (lg2[tid][qq] > bv) { bv = lg2[tid][qq]; best = qq; }
        n2s[tid] = best;
    }
    __syncthreads();

    if (tid < EL) {
        const int m = tid / ORIG;
        out_dec[(size_t)(i0 + 0) * EL + tid] = (m < n2s[0]) ? dreg.x : 0.f;
        out_dec[(size_t)(i0 + 1) * EL + tid] = (m < n2s[1]) ? dreg.y : 0.f;
        out_dec[(size_t)(i0 + 2) * EL + tid] = (m < n2s[2]) ? dreg.z : 0.f;
        out_dec[(size_t)(i0 + 3) * EL + tid] = (m < n2s[3]) ? dreg.w : 0.f;
    } else if (tid >= NTHR - G * MAXO) {
        const int idx = tid - (NTHR - G * MAXO);
        const int g = idx >> 4, m = idx & 15;
        out_batch[(i0 + g) * MAXO + m] = (float)(i0 + g);
        out_mask[(i0 + g) * MAXO + m]  = (m < n2s[g]) ? 1.f : 0.f;
    }
}

extern "C" void kernel_launch(void* const* d_in, const int* in_sizes, int n_in,
                              void* d_out, int out_size, void* d_ws, size_t ws_size,
                              hipStream_t stream)
{
    const float* obj_x     = (const float*)d_in[0];
    const float* obj_pos   = (const float*)d_in[1];
    const float* agent_pos = (const float*)d_in[2];
    const float* enc_W1    = (const float*)d_in[3];
    const float* enc_b1    = (const float*)d_in[4];
    const float* enc_W2    = (const float*)d_in[5];
    const float* enc_b2    = (const float*)d_in[6];
    const float* mdec_Ws   = (const float*)d_in[7];
    const float* mdec_bs   = (const float*)d_in[8];
    const float* mdec_Wx   = (const float*)d_in[9];
    const float* mdec_bx   = (const float*)d_in[10];
    const float* menc_W1   = (const float*)d_in[11];
    const float* menc_b1   = (const float*)d_in[12];
    const float* menc_W2   = (const float*)d_in[13];
    const float* menc_b2   = (const float*)d_in[14];
    const float* dec_Ws    = (const float*)d_in[15];
    const float* dec_bs    = (const float*)d_in[16];
    const float* dec_Wx    = (const float*)d_in[17];
    const float* dec_bx    = (const float*)d_in[18];
    const int*   obs_edge  = (const int*)d_in[19];
    const int*   comm_edge = (const int*)d_in[20];

    char* ws = (char*)d_ws;
    float*  elems_base = (float*)ws;                                    // 4096*288 f32
    int*    npred      = (int*)(ws + (size_t)A_N * EL * sizeof(float)); // 4096 i32
    float2* pxy_base   = (float2*)(ws + (size_t)A_N * EL * sizeof(float)
                                      + (size_t)A_N * sizeof(int));    // 4096*16 float2

    float* out_dec   = (float*)d_out;
    float* out_batch = out_dec + (size_t)A_N * EL;
    float* out_mask  = out_batch + (size_t)A_N * MAXO;

    enc512_kernel<<<NBLK, NTHR, 0, stream>>>(
        obj_x, obj_pos, agent_pos, enc_W1, enc_b1, enc_W2, enc_b2,
        mdec_Ws, mdec_bs, mdec_Wx, mdec_bx, obs_edge,
        elems_base, npred, pxy_base);

    merge512_kernel<<<NBLK, NTHR, 0, stream>>>(
        agent_pos, menc_W1, menc_b1, menc_W2, menc_b2,
        dec_Ws, dec_bs, dec_Wx, dec_bx, comm_edge,
        elems_base, npred, pxy_base, out_dec, out_batch, out_mask);
}